// Round 4
// baseline (1624.157 us; speedup 1.0000x reference)
//
#include <hip/hip_runtime.h>
#include <cstdint>
#include <cstddef>

// Problem constants (from reference): N=100000, F_IN=512, HID=256, C=64, E=3.2e6, K=5
#define NF_IN 512
#define NHID 256
#define NC 64

typedef _Float16 f16x8 __attribute__((ext_vector_type(8)));
typedef float f32x4 __attribute__((ext_vector_type(4)));

// ---------------- bucketized CSR build ----------------
// Buckets: dst>>8 (256 nodes/bucket). NBK = (n+255)>>8 <= 512.
__global__ void kb_hist(const int* __restrict__ dst, int e_total,
                        int* __restrict__ gh, int nbk){
  __shared__ int h[512];
  int t = threadIdx.x;
  for (int i=t;i<nbk;i+=256) h[i]=0;
  __syncthreads();
  int e0 = blockIdx.x*4096;
  #pragma unroll
  for (int j=0;j<16;j++){
    int e = e0 + j*256 + t;
    if (e < e_total) atomicAdd(&h[dst[e]>>8], 1);
  }
  __syncthreads();
  for (int i=t;i<nbk;i+=256) if (h[i]) atomicAdd(&gh[i], h[i]);
}

// single-block in-place exclusive scan (n <= 256*chunk)
__global__ void k_scan1(int* __restrict__ data, int n){
  __shared__ int P[256];
  int t = threadIdx.x;
  int chunk = (n + 255) >> 8;
  int base = t*chunk;
  int s = 0;
  for (int j=0;j<chunk;j++) if (base+j<n) s += data[base+j];
  P[t]=s; __syncthreads();
  for (int o=1;o<256;o<<=1){
    int v = (t>=o)? P[t-o]:0; __syncthreads();
    P[t]+=v; __syncthreads();
  }
  int run = (t>0)? P[t-1] : 0;
  for (int j=0;j<chunk;j++) if (base+j<n){ int v = data[base+j]; data[base+j]=run; run+=v; }
}

// exclusive scan + copy of scanned values into a cursor array
__global__ void kb_scan1c(int* __restrict__ data, int* __restrict__ cpy, int n){
  __shared__ int P[256];
  int t = threadIdx.x;
  int chunk = (n + 255) >> 8;
  int base = t*chunk;
  int s = 0;
  for (int j=0;j<chunk;j++) if (base+j<n) s += data[base+j];
  P[t]=s; __syncthreads();
  for (int o=1;o<256;o<<=1){
    int v = (t>=o)? P[t-o]:0; __syncthreads();
    P[t]+=v; __syncthreads();
  }
  int run = (t>0)? P[t-1] : 0;
  for (int j=0;j<chunk;j++) if (base+j<n){ int v = data[base+j]; data[base+j]=run; cpy[base+j]=run; run+=v; }
}

__global__ void kb_scatter(const int* __restrict__ src, const int* __restrict__ dst,
                           int e_total, int* __restrict__ bcur,
                           unsigned* __restrict__ pairs, int nbk){
  __shared__ int h[512];
  __shared__ int cb[512];
  int t = threadIdx.x;
  for (int i=t;i<nbk;i+=256) h[i]=0;
  __syncthreads();
  int e0 = blockIdx.x*4096;
  int d[16], s_[16];
  #pragma unroll
  for (int j=0;j<16;j++){
    int e = e0 + j*256 + t;
    if (e < e_total){ d[j]=dst[e]; s_[j]=src[e]; atomicAdd(&h[d[j]>>8],1); }
    else d[j] = -1;
  }
  __syncthreads();
  for (int i=t;i<nbk;i+=256){
    int c = h[i];
    cb[i] = c ? atomicAdd(&bcur[i], c) : 0;
    h[i] = 0;
  }
  __syncthreads();
  #pragma unroll
  for (int j=0;j<16;j++){
    if (d[j] >= 0){
      int bkt = d[j]>>8;
      int pos = cb[bkt] + atomicAdd(&h[bkt],1);
      pairs[pos] = ((unsigned)(d[j]&255)<<24) | (unsigned)s_[j];
    }
  }
}

__global__ __launch_bounds__(256) void kb_build(const unsigned* __restrict__ pairs,
    const int* __restrict__ bbase, int e_total, int nbk, int n,
    int* __restrict__ rowptr, int* __restrict__ cnt, float* __restrict__ dinv,
    int* __restrict__ csr){
  __shared__ int cL[256];
  __shared__ int sc[256];
  __shared__ int rpL[256];
  int b = blockIdx.x, t = threadIdx.x;
  int beg = bbase[b];
  int end = (b == nbk-1) ? e_total : bbase[b+1];
  cL[t] = 0; __syncthreads();
  for (int i=beg+t; i<end; i+=256) atomicAdd(&cL[pairs[i]>>24], 1);
  __syncthreads();
  int v = cL[t]; sc[t] = v; __syncthreads();
  for (int o=1;o<256;o<<=1){
    int w = (t>=o)? sc[t-o]:0; __syncthreads();
    sc[t] += w; __syncthreads();
  }
  rpL[t] = sc[t] - v;            // exclusive
  int node = b*256 + t;
  if (node < n){
    rowptr[node] = beg + rpL[t];
    cnt[node]    = v;
    dinv[node]   = 1.0f / sqrtf((float)(v + 1));
  }
  cL[t] = 0; __syncthreads();
  for (int i=beg+t; i<end; i+=256){
    unsigned p = pairs[i];
    int loc = p >> 24;
    int pos = beg + rpL[loc] + atomicAdd(&cL[loc], 1);
    csr[pos] = (int)(p & 0xFFFFFFu);
  }
}

// ---------------- W1 split: fp32 [K=512][N=256] -> hi/lo fp16 transposed [N][K] ----------------
__global__ void k_wsplit(const float* __restrict__ W, _Float16* __restrict__ WhT,
                         _Float16* __restrict__ WlT){
  int idx = blockIdx.x*256 + threadIdx.x;
  if (idx < NF_IN*NHID){
    int k = idx >> 8, nn = idx & 255;        // W row-major [512][256]
    float w = W[idx];
    _Float16 h = (_Float16)w;
    _Float16 l = (_Float16)((w - (float)h) * 2048.0f);
    WhT[(size_t)nn*NF_IN + k] = h;
    WlT[(size_t)nn*NF_IN + k] = l;
  }
}

// ---------------- split-fp16 MFMA GEMM for layer 1 (fp32-accurate) ----------------
__global__ __launch_bounds__(512, 2) void k_mgemm1(
    const float* __restrict__ A, int lda,
    const _Float16* __restrict__ BhT, const _Float16* __restrict__ BlT, int ldb,
    float* __restrict__ C, int ldc, int M, int K, const float* __restrict__ dinv){
  __shared__ __align__(16) _Float16 Ah[128*40];
  __shared__ __align__(16) _Float16 Al[128*40];
  __shared__ __align__(16) _Float16 Bh[256*40];
  __shared__ __align__(16) _Float16 Bl[256*40];
  int t = threadIdx.x;
  int m0 = blockIdx.x*128;
  int wave = t>>6, lane = t&63;
  int wm = (wave>>2)*64, wn = (wave&3)*64;

  int arow = t>>2, akb = (t&3)*8;
  int ga = m0 + arow; if (ga >= M) ga = M - 1;
  const float* aptr = A + (size_t)ga*lda + akb;
  int brow = t>>1, bkb = (t&1)*16;
  const _Float16* bhp = BhT + (size_t)brow*ldb + bkb;
  const _Float16* blp = BlT + (size_t)brow*ldb + bkb;

  float4 a0 = *(const float4*)(aptr);
  float4 a1 = *(const float4*)(aptr+4);
  f16x8  b0 = *(const f16x8*)(bhp);
  f16x8  b1 = *(const f16x8*)(bhp+8);
  f16x8  c0 = *(const f16x8*)(blp);
  f16x8  c1 = *(const f16x8*)(blp+8);

  f32x4 acc1[4][4] = {};   // hi*hi
  f32x4 acc2[4][4] = {};   // hi*lo' + lo'*hi (scaled by 2^11)

  for (int k0 = 0; k0 < K; k0 += 32){
    __syncthreads();
    {
      float av[8] = {a0.x,a0.y,a0.z,a0.w, a1.x,a1.y,a1.z,a1.w};
      f16x8 h0, l0;
      #pragma unroll
      for (int j=0;j<8;j++){
        _Float16 hh = (_Float16)av[j];
        h0[j] = hh;
        l0[j] = (_Float16)((av[j] - (float)hh) * 2048.0f);
      }
      *(f16x8*)&Ah[arow*40+akb] = h0;
      *(f16x8*)&Al[arow*40+akb] = l0;
      *(f16x8*)&Bh[brow*40+bkb]   = b0;
      *(f16x8*)&Bh[brow*40+bkb+8] = b1;
      *(f16x8*)&Bl[brow*40+bkb]   = c0;
      *(f16x8*)&Bl[brow*40+bkb+8] = c1;
    }
    __syncthreads();
    if (k0 + 32 < K){
      a0 = *(const float4*)(aptr + k0+32);
      a1 = *(const float4*)(aptr + k0+36);
      b0 = *(const f16x8*)(bhp + k0+32);
      b1 = *(const f16x8*)(bhp + k0+40);
      c0 = *(const f16x8*)(blp + k0+32);
      c1 = *(const f16x8*)(blp + k0+40);
    }
    int fr = lane & 15, fk = (lane>>4)*8;
    f16x8 afh[4], afl[4];
    #pragma unroll
    for (int mf=0; mf<4; mf++){
      afh[mf] = *(const f16x8*)&Ah[(wm + mf*16 + fr)*40 + fk];
      afl[mf] = *(const f16x8*)&Al[(wm + mf*16 + fr)*40 + fk];
    }
    #pragma unroll
    for (int nf=0; nf<4; nf++){
      f16x8 bfh = *(const f16x8*)&Bh[(wn + nf*16 + fr)*40 + fk];
      f16x8 bfl = *(const f16x8*)&Bl[(wn + nf*16 + fr)*40 + fk];
      #pragma unroll
      for (int mf=0; mf<4; mf++){
        acc1[mf][nf] = __builtin_amdgcn_mfma_f32_16x16x32_f16(afh[mf], bfh, acc1[mf][nf], 0, 0, 0);
        acc2[mf][nf] = __builtin_amdgcn_mfma_f32_16x16x32_f16(afh[mf], bfl, acc2[mf][nf], 0, 0, 0);
        acc2[mf][nf] = __builtin_amdgcn_mfma_f32_16x16x32_f16(afl[mf], bfh, acc2[mf][nf], 0, 0, 0);
      }
    }
  }

  int fr = lane & 15, fq = lane >> 4;
  #pragma unroll
  for (int mf=0; mf<4; mf++){
    #pragma unroll
    for (int i=0;i<4;i++){
      int row = m0 + wm + mf*16 + fq*4 + i;
      if (row < M){
        float sc = dinv ? dinv[row] : 1.0f;
        #pragma unroll
        for (int nf=0; nf<4; nf++){
          float v = (acc1[mf][nf][i] + 0.00048828125f*acc2[mf][nf][i]) * sc;
          C[(size_t)row*ldc + wn + nf*16 + fr] = v;
        }
      }
    }
  }
}

// ---------------- tiled fp32 GEMM (64-wide N), kept for GEMM2 ----------------
__global__ __launch_bounds__(256) void k_gemm(const float* __restrict__ A, int lda,
    const float* __restrict__ B, int ldb, float* __restrict__ C, int ldc,
    int M, int K, const float* __restrict__ dinv){
  __shared__ float As[16*68];   // [k][m], padded stride 68
  __shared__ float Bs[16*64];   // [k][n]
  int t = threadIdx.x;
  int m0 = blockIdx.x*64, n0 = blockIdx.y*64;
  int tx = t & 15, ty = t >> 4;
  float acc[4][4] = {};
  int arow = m0 + (t>>2); if (arow >= M) arow = M-1;
  const float* aptr = A + (size_t)arow*lda + (t&3)*4;
  const float* bptr = B + (size_t)(t>>4)*ldb + n0 + (t&15)*4;
  for (int k0=0; k0<K; k0+=16){
    float4 av = *(const float4*)(aptr + k0);
    float4 bv = *(const float4*)(bptr + (size_t)k0*ldb);
    __syncthreads();
    int ak = (t&3)*4, ar = t>>2;
    As[(ak+0)*68 + ar] = av.x;
    As[(ak+1)*68 + ar] = av.y;
    As[(ak+2)*68 + ar] = av.z;
    As[(ak+3)*68 + ar] = av.w;
    *(float4*)&Bs[(t>>4)*64 + (t&15)*4] = bv;
    __syncthreads();
    #pragma unroll
    for (int kk=0;kk<16;kk++){
      float4 a4 = *(const float4*)&As[kk*68 + (ty<<2)];
      float4 b4 = *(const float4*)&Bs[(kk<<6) + (tx<<2)];
      float aa[4] = {a4.x,a4.y,a4.z,a4.w};
      float bb[4] = {b4.x,b4.y,b4.z,b4.w};
      #pragma unroll
      for (int i=0;i<4;i++)
        #pragma unroll
        for (int j=0;j<4;j++) acc[i][j] += aa[i]*bb[j];
    }
  }
  #pragma unroll
  for (int i=0;i<4;i++){
    int row = m0 + (ty<<2) + i;
    if (row < M){
      float sc = dinv ? dinv[row] : 1.0f;
      float4 vv; vv.x=acc[i][0]*sc; vv.y=acc[i][1]*sc; vv.z=acc[i][2]*sc; vv.w=acc[i][3]*sc;
      *(float4*)&C[(size_t)row*ldc + n0 + (tx<<2)] = vv;
    }
  }
}

// ---------------- GCN aggregation (256-ch): wave/node, float4/lane ----------------
__global__ __launch_bounds__(256, 4) void k_agg1(const float* __restrict__ u,
    const int* __restrict__ rowptr, const int* __restrict__ cnt,
    const int* __restrict__ csr, const float* __restrict__ dinv,
    const float* __restrict__ bias, float* __restrict__ outp, int n){
  int wid = blockIdx.x*4 + (threadIdx.x>>6);
  int lane = threadIdx.x & 63;
  if (wid >= n) return;
  const float4* up = (const float4*)u;
  float4 a = up[(size_t)wid*64 + lane];       // self term
  float ax=a.x, ay=a.y, az=a.z, aw=a.w;
  int beg = rowptr[wid], num = cnt[wid];
  int e = 0;
  int nb = num >> 4;
  if (nb > 0){
    int my = csr[beg + (lane & 15)];
    float4 v[8], w[8];
    #pragma unroll
    for (int q=0;q<8;q++){ int s = __shfl(my, q); v[q] = up[(size_t)s*64 + lane]; }
    int b = 0;
    for (;;){
      #pragma unroll
      for (int q=0;q<8;q++){ int s = __shfl(my, q+8); w[q] = up[(size_t)s*64 + lane]; }
      #pragma unroll
      for (int q=0;q<8;q++){ ax+=v[q].x; ay+=v[q].y; az+=v[q].z; aw+=v[q].w; }
      b++;
      if (b >= nb){
        #pragma unroll
        for (int q=0;q<8;q++){ ax+=w[q].x; ay+=w[q].y; az+=w[q].z; aw+=w[q].w; }
        break;
      }
      my = csr[beg + b*16 + (lane & 15)];
      #pragma unroll
      for (int q=0;q<8;q++){ int s = __shfl(my, q); v[q] = up[(size_t)s*64 + lane]; }
      #pragma unroll
      for (int q=0;q<8;q++){ ax+=w[q].x; ay+=w[q].y; az+=w[q].z; aw+=w[q].w; }
    }
    e = nb*16;
  }
  for (; e+4 <= num; e+=4){
    int my = csr[beg + e + (lane & 3)];
    float4 v[4];
    #pragma unroll
    for (int q=0;q<4;q++){ int s = __shfl(my, q); v[q] = up[(size_t)s*64 + lane]; }
    #pragma unroll
    for (int q=0;q<4;q++){ ax+=v[q].x; ay+=v[q].y; az+=v[q].z; aw+=v[q].w; }
  }
  for (; e<num; e++){
    int sN = csr[beg+e];
    float4 v = up[(size_t)sN*64 + lane];
    ax+=v.x; ay+=v.y; az+=v.z; aw+=v.w;
  }
  float di = dinv[wid];
  float4 b = ((const float4*)bias)[lane];
  float4 r;
  r.x = fmaxf(di*ax + b.x, 0.f);
  r.y = fmaxf(di*ay + b.y, 0.f);
  r.z = fmaxf(di*az + b.z, 0.f);
  r.w = fmaxf(di*aw + b.w, 0.f);
  ((float4*)outp)[(size_t)wid*64 + lane] = r;
}

// 64-channel aggregation + fused g-score / sort-key generation
__global__ __launch_bounds__(256) void k_agg2g(const float* __restrict__ u,
    const int* __restrict__ rowptr, const int* __restrict__ cnt,
    const int* __restrict__ csr, const float* __restrict__ dinv,
    const float* __restrict__ bias, float* __restrict__ outp, int n,
    const float* __restrict__ Wp, const float* __restrict__ bp,
    float* __restrict__ g, unsigned* __restrict__ keys, unsigned* __restrict__ vals){
  int wid = blockIdx.x*4 + (threadIdx.x>>6);
  int lane = threadIdx.x & 63;
  if (wid >= n) return;
  float acc = u[(size_t)wid*64 + lane];
  int beg = rowptr[wid], num = cnt[wid];
  int e = 0;
  for (; e+16 <= num; e+=16){
    int my = csr[beg + e + (lane & 15)];
    float v[16];
    #pragma unroll
    for (int q=0;q<16;q++){ int s = __shfl(my, q); v[q] = u[(size_t)s*64 + lane]; }
    #pragma unroll
    for (int q=0;q<16;q++) acc += v[q];
  }
  for (; e+4 <= num; e+=4){
    int my = csr[beg + e + (lane & 3)];
    float v[4];
    #pragma unroll
    for (int q=0;q<4;q++){ int s = __shfl(my, q); v[q] = u[(size_t)s*64 + lane]; }
    #pragma unroll
    for (int q=0;q<4;q++) acc += v[q];
  }
  for (; e<num; e++){
    int sN = csr[beg+e];
    acc += u[(size_t)sN*64 + lane];
  }
  float val = dinv[wid]*acc + bias[lane];
  outp[(size_t)wid*64 + lane] = val;
  float wv = val * Wp[lane];
  for (int o=32;o>0;o>>=1) wv += __shfl_xor(wv, o);
  if (lane == 0){
    float gg = wv + bp[0];
    g[wid] = gg;
    unsigned u_ = __float_as_uint(gg);
    u_ = (u_>>31) ? ~u_ : (u_ | 0x80000000u);
    keys[wid] = u_; vals[wid] = (unsigned)wid;
  }
}

// ---------------- stable 8-bit LSD radix sort (1024 elems/block, 4 passes) ----------------
// Initial 256-bin histogram (pass 0 only); later passes' histograms are built by the
// previous pass's scatter (it knows each element's output position).
__global__ void k_rhist8(const unsigned* __restrict__ keys, int shift,
                         int* __restrict__ gh, int n, int nb){
  __shared__ int h[256];
  int t = threadIdx.x;
  h[t] = 0;
  __syncthreads();
  int base = blockIdx.x*1024 + t*4;
  #pragma unroll
  for (int j=0;j<4;j++)
    if (base+j < n) atomicAdd(&h[(keys[base+j]>>shift)&255], 1);
  __syncthreads();
  gh[t*nb + blockIdx.x] = h[t];
}

// Stable 256-bin scatter. In-block stable rank = cross-wave prefix (LDS hist) +
// in-wave ballot rank (8 ballots per item-slot; memory order within wave is lane*4+j).
__global__ __launch_bounds__(256) void k_rscat8(
    const unsigned* __restrict__ keys, const unsigned* __restrict__ vals,
    int shift, const int* __restrict__ gbase, int nb,
    unsigned* __restrict__ okeys, unsigned* __restrict__ ovals,
    int* __restrict__ gh_next, int next_shift, int n){
  __shared__ int whist[4][256];
  __shared__ int wbase[4][256];
  int t = threadIdx.x;
  int w = t>>6, lane = t&63;
  #pragma unroll
  for (int q=0;q<4;q++) whist[q][t] = 0;
  __syncthreads();
  int base = blockIdx.x*1024 + t*4;
  unsigned k[4], v[4]; int d[4]; bool ok[4];
  #pragma unroll
  for (int j=0;j<4;j++){
    ok[j] = (base+j < n);
    k[j] = ok[j] ? keys[base+j] : 0u;
    v[j] = ok[j] ? vals[base+j] : 0u;
    d[j] = (int)((k[j]>>shift)&255u);
    if (ok[j]) atomicAdd(&whist[w][d[j]], 1);
  }
  __syncthreads();
  {
    int c0=whist[0][t], c1=whist[1][t], c2=whist[2][t];
    wbase[0][t]=0; wbase[1][t]=c0; wbase[2][t]=c0+c1; wbase[3][t]=c0+c1+c2;
  }
  __syncthreads();
  // in-wave stable rank via ballots
  int rank[4] = {0,0,0,0};
  unsigned long long below = (lane==0)? 0ull : ((~0ull) >> (64-lane));
  unsigned long long self  = 1ull << lane;
  #pragma unroll
  for (int jp=0; jp<4; jp++){
    unsigned long long B0 = __ballot((d[jp]>>0)&1);
    unsigned long long B1 = __ballot((d[jp]>>1)&1);
    unsigned long long B2 = __ballot((d[jp]>>2)&1);
    unsigned long long B3 = __ballot((d[jp]>>3)&1);
    unsigned long long B4 = __ballot((d[jp]>>4)&1);
    unsigned long long B5 = __ballot((d[jp]>>5)&1);
    unsigned long long B6 = __ballot((d[jp]>>6)&1);
    unsigned long long B7 = __ballot((d[jp]>>7)&1);
    unsigned long long Vb = __ballot(ok[jp]);
    #pragma unroll
    for (int j=0;j<4;j++){
      unsigned long long m = Vb;
      m &= ((d[j]>>0)&1) ? B0 : ~B0;
      m &= ((d[j]>>1)&1) ? B1 : ~B1;
      m &= ((d[j]>>2)&1) ? B2 : ~B2;
      m &= ((d[j]>>3)&1) ? B3 : ~B3;
      m &= ((d[j]>>4)&1) ? B4 : ~B4;
      m &= ((d[j]>>5)&1) ? B5 : ~B5;
      m &= ((d[j]>>6)&1) ? B6 : ~B6;
      m &= ((d[j]>>7)&1) ? B7 : ~B7;
      unsigned long long sel = (jp < j) ? (below | self) : below;
      rank[j] += __popcll(m & sel);
    }
  }
  #pragma unroll
  for (int j=0;j<4;j++){
    if (ok[j]){
      int dd = d[j];
      int pos = gbase[dd*nb + blockIdx.x] + wbase[w][dd] + rank[j];
      okeys[pos] = k[j];
      ovals[pos] = v[j];
      if (gh_next){
        int nd = (int)((k[j]>>next_shift)&255u);
        atomicAdd(&gh_next[nd*nb + (pos>>10)], 1);
      }
    }
  }
}

// ---------------- sorted seq build, inverse perm ----------------
__global__ void k_ssx(const unsigned* __restrict__ sidx, const float* __restrict__ g,
                      const float* __restrict__ x1, float* __restrict__ ssx,
                      int* __restrict__ inv, int n){
  int idx = blockIdx.x*256 + threadIdx.x;
  if (idx < n*64){
    int p = idx>>6, c = idx&63;
    int j = (int)sidx[p];
    ssx[idx] = g[j] * x1[(size_t)j*64 + c];
    if (c==0) inv[j] = p;
  }
}

// conv weight transpose [co][ci][k] -> [k][ci][co]
__global__ void k_wt(const float* __restrict__ cw1, const float* __restrict__ cw2,
                     float* __restrict__ wT1, float* __restrict__ wT2){
  int idx = blockIdx.x*256 + threadIdx.x;
  if (idx < 2*20480){
    const float* s = (idx < 20480) ? cw1 : cw2;
    float* o = (idx < 20480) ? wT1 : wT2;
    int i = idx % 20480;
    int kk = i % 5, ci = (i/5) % 64, co = i / 320;
    o[((kk<<6)+ci)*64 + co] = s[i];
  }
}

// ---------------- direct conv1d, C=64, K=5, SAME ----------------
__global__ __launch_bounds__(256) void k_conv(const float* __restrict__ inp,
    const float* __restrict__ wT, const float* __restrict__ bias,
    float* __restrict__ outp, int n, int do_relu){
  __shared__ float xin[132*65];    // rows r0-2 .. r0+129, stride 65
  int t = threadIdx.x;
  int r0 = blockIdx.x*128;
  for (int idx=t; idx<132*64; idx+=256){
    int r = idx>>6, c = idx&63;
    int gr = r0 + r - 2;
    xin[r*65 + c] = (gr>=0 && gr<n) ? inp[(size_t)gr*64 + c] : 0.f;
  }
  __syncthreads();
  int rg = t & 15, cg = t >> 4;
  float acc[8][4] = {};
  for (int k=0;k<5;k++){
    for (int ci=0;ci<64;ci++){
      float4 w = *(const float4*)&wT[((k<<6)+ci)*64 + (cg<<2)];
      #pragma unroll
      for (int rr=0;rr<8;rr++){
        float xv = xin[(rg + (rr<<4) + k)*65 + ci];
        acc[rr][0] += xv*w.x; acc[rr][1] += xv*w.y;
        acc[rr][2] += xv*w.z; acc[rr][3] += xv*w.w;
      }
    }
  }
  float4 b = ((const float4*)bias)[cg];
  #pragma unroll
  for (int rr=0;rr<8;rr++){
    int row = r0 + rg + (rr<<4);
    if (row < n){
      float4 v;
      v.x = acc[rr][0]+b.x; v.y = acc[rr][1]+b.y; v.z = acc[rr][2]+b.z; v.w = acc[rr][3]+b.w;
      if (do_relu){ v.x=fmaxf(v.x,0.f); v.y=fmaxf(v.y,0.f); v.z=fmaxf(v.z,0.f); v.w=fmaxf(v.w,0.f); }
      *(float4*)&outp[(size_t)row*64 + (cg<<2)] = v;
    }
  }
}

// ---------------- fused final: [x1 | y2[inv]] @ Wl + bl -> log_softmax -> out ----------------
__global__ __launch_bounds__(256) void k_fgemm(const float* __restrict__ x1,
    const float* __restrict__ y2, const int* __restrict__ inv,
    const float* __restrict__ Wl, const float* __restrict__ bl,
    float* __restrict__ outp, int M){
  __shared__ float As[16*68];
  __shared__ float Bs[16*64];
  __shared__ float Pr[64*16];
  __shared__ float Ms[64];
  __shared__ float Ls[64];
  int t = threadIdx.x;
  int m0 = blockIdx.x*64;
  int tx = t & 15, ty = t >> 4;
  float acc[4][4] = {};
  int arow = m0 + (t>>2); if (arow >= M) arow = M-1;
  int acol0 = (t&3)*4;
  int invr = inv[arow];
  const float* bptr = Wl + (size_t)(t>>4)*64 + tx*4;
  for (int k0=0; k0<128; k0+=16){
    int acol = acol0 + k0;
    float4 av = (acol < 64) ? *(const float4*)&x1[(size_t)arow*64 + acol]
                            : *(const float4*)&y2[(size_t)invr*64 + (acol-64)];
    float4 bv = *(const float4*)(bptr + (size_t)k0*64);
    __syncthreads();
    int ak = (t&3)*4, ar = t>>2;
    As[(ak+0)*68 + ar] = av.x;
    As[(ak+1)*68 + ar] = av.y;
    As[(ak+2)*68 + ar] = av.z;
    As[(ak+3)*68 + ar] = av.w;
    *(float4*)&Bs[(t>>4)*64 + (t&15)*4] = bv;
    __syncthreads();
    #pragma unroll
    for (int kk=0;kk<16;kk++){
      float4 a4 = *(const float4*)&As[kk*68 + (ty<<2)];
      float4 b4 = *(const float4*)&Bs[(kk<<6) + (tx<<2)];
      float aa[4] = {a4.x,a4.y,a4.z,a4.w};
      float bb[4] = {b4.x,b4.y,b4.z,b4.w};
      #pragma unroll
      for (int i=0;i<4;i++)
        #pragma unroll
        for (int j=0;j<4;j++) acc[i][j] += aa[i]*bb[j];
    }
  }
  float v[4][4];
  #pragma unroll
  for (int i=0;i<4;i++)
    #pragma unroll
    for (int j=0;j<4;j++) v[i][j] = acc[i][j] + bl[(tx<<2)+j];
  #pragma unroll
  for (int i=0;i<4;i++){
    float pm = fmaxf(fmaxf(v[i][0],v[i][1]), fmaxf(v[i][2],v[i][3]));
    Pr[((ty<<2)+i)*16 + tx] = pm;
  }
  __syncthreads();
  if (t < 64){
    float m = Pr[t*16];
    #pragma unroll
    for (int k=1;k<16;k++) m = fmaxf(m, Pr[t*16+k]);
    Ms[t] = m;
  }
  __syncthreads();
  #pragma unroll
  for (int i=0;i<4;i++){
    float m = Ms[(ty<<2)+i];
    float ps = expf(v[i][0]-m)+expf(v[i][1]-m)+expf(v[i][2]-m)+expf(v[i][3]-m);
    Pr[((ty<<2)+i)*16 + tx] = ps;
  }
  __syncthreads();
  if (t < 64){
    float s = 0.f;
    #pragma unroll
    for (int k=0;k<16;k++) s += Pr[t*16+k];
    Ls[t] = logf(s);
  }
  __syncthreads();
  #pragma unroll
  for (int i=0;i<4;i++){
    int row = m0 + (ty<<2) + i;
    if (row < M){
      float m = Ms[(ty<<2)+i], l = Ls[(ty<<2)+i];
      float4 o;
      o.x = v[i][0]-m-l; o.y = v[i][1]-m-l; o.z = v[i][2]-m-l; o.w = v[i][3]-m-l;
      *(float4*)&outp[(size_t)row*64 + (tx<<2)] = o;
    }
  }
}

// ---------------- launch ----------------
extern "C" void kernel_launch(void* const* d_in, const int* in_sizes, int n_in,
                              void* d_out, int out_size, void* d_ws, size_t ws_size,
                              hipStream_t stream) {
  const float* x   = (const float*)d_in[0];
  const int*   ei  = (const int*)d_in[1];
  const float* W1  = (const float*)d_in[2];
  const float* b1  = (const float*)d_in[3];
  const float* W2  = (const float*)d_in[4];
  const float* b2  = (const float*)d_in[5];
  const float* Wp  = (const float*)d_in[6];
  const float* bp  = (const float*)d_in[7];
  const float* cw1 = (const float*)d_in[8];
  const float* cb1 = (const float*)d_in[9];
  const float* cw2 = (const float*)d_in[10];
  const float* cb2 = (const float*)d_in[11];
  const float* Wl  = (const float*)d_in[12];
  const float* bl  = (const float*)d_in[13];
  float* out = (float*)d_out;

  const int n = in_sizes[0] / NF_IN;        // 100000
  const int e_total = in_sizes[1] / 2;      // 3200000
  const int* srcp = ei;
  const int* dstp = ei + e_total;

  char* ws = (char*)d_ws;
  size_t off = 0;
  auto take = [&](size_t bytes)->char* {
    char* p = ws + off; off = (off + bytes + 255) & ~(size_t)255; return p;
  };
  const int NB  = (n + 1023) / 1024;        // radix-sort blocks (98)
  const int NBK = (n + 255) >> 8;           // CSR buckets (391), <= 512
  const int NEB = (e_total + 4095) / 4096;  // edge blocks (782)
  int*      cnt    = (int*)     take((size_t)n*4);
  int*      rowptr = (int*)     take((size_t)n*4);
  float*    dinv   = (float*)   take((size_t)n*4);
  float*    g      = (float*)   take((size_t)n*4);
  int*      inv    = (int*)     take((size_t)n*4);
  unsigned* keys0  = (unsigned*)take((size_t)n*4);
  unsigned* vals0  = (unsigned*)take((size_t)n*4);
  unsigned* keys1  = (unsigned*)take((size_t)n*4);
  unsigned* vals1  = (unsigned*)take((size_t)n*4);
  int*      ghA    = (int*)     take((size_t)(256*NB)*4);
  int*      ghB    = (int*)     take((size_t)(256*NB)*4);
  int*      bh     = (int*)     take(512*4);
  int*      bcur   = (int*)     take(512*4);
  int*      csr    = (int*)     take((size_t)e_total*4);
  float*    wT1    = (float*)   take(20480*4);
  float*    wT2    = (float*)   take(20480*4);
  _Float16* w1h    = (_Float16*)take((size_t)NF_IN*NHID*2);
  _Float16* w1l    = (_Float16*)take((size_t)NF_IN*NHID*2);
  float*    bigA   = (float*)   take((size_t)n*256*4);
  float*    bigB   = (float*)   take((size_t)n*256*4);
  unsigned* pairs  = (unsigned*)bigA;       // transient: consumed before u1 written
  float* u1  = bigA;
  float* h   = bigB;
  float* u2  = bigA;
  float* x1  = bigA + (size_t)n*64;
  float* ssx = bigA + (size_t)n*128;
  float* y1  = bigA + (size_t)n*192;
  float* y2  = bigB;

  const int nb128 = (n + 127) / 128;
  const int nb64  = (n + 63) / 64;
  const int nbAgg = (n + 3) / 4;

  // bucketized CSR build (+ cnt/rowptr/dinv)
  hipMemsetAsync(bh, 0, (size_t)NBK*4, stream);
  kb_hist<<<NEB, 256, 0, stream>>>(dstp, e_total, bh, NBK);
  kb_scan1c<<<1, 256, 0, stream>>>(bh, bcur, NBK);
  kb_scatter<<<NEB, 256, 0, stream>>>(srcp, dstp, e_total, bcur, pairs, NBK);
  kb_build<<<NBK, 256, 0, stream>>>(pairs, bh, e_total, NBK, n, rowptr, cnt, dinv, csr);

  // GCN layer 1: u1 = dinv .* (x @ W1) via split-fp16 MFMA (BN=256, A read once)
  k_wsplit<<<(NF_IN*NHID+255)/256, 256, 0, stream>>>(W1, w1h, w1l);
  k_mgemm1<<<dim3(nb128, 1), 512, 0, stream>>>(x, NF_IN, w1h, w1l, NF_IN, u1, NHID, n, NF_IN, dinv);
  // h = relu(agg(u1) + b1)
  k_agg1<<<nbAgg, 256, 0, stream>>>(u1, rowptr, cnt, csr, dinv, b1, h, n);

  // GCN layer 2: u2 = dinv .* (h @ W2); x1 = agg(u2) + b2 (+ fused g-score/sort keys)
  k_gemm<<<dim3(nb64, 1), 256, 0, stream>>>(h, NHID, W2, NC, u2, NC, n, NHID, dinv);
  k_agg2g<<<nbAgg, 256, 0, stream>>>(u2, rowptr, cnt, csr, dinv, b2, x1, n,
                                     Wp, bp, g, keys0, vals0);

  // stable radix sort, 4 x 8-bit passes (scatter of pass p builds pass p+1's histogram)
  {
    unsigned *ka = keys0, *va = vals0, *kb = keys1, *vb = vals1;
    int *gcur = ghA, *gnext = ghB;
    k_rhist8<<<NB, 256, 0, stream>>>(ka, 0, gcur, n, NB);
    for (int p = 0; p < 4; p++){
      if (p < 3) hipMemsetAsync(gnext, 0, (size_t)(256*NB)*4, stream);
      k_scan1<<<1, 256, 0, stream>>>(gcur, 256*NB);
      k_rscat8<<<NB, 256, 0, stream>>>(ka, va, p*8, gcur, NB, kb, vb,
                                       (p<3)? gnext : nullptr, (p<3)? (p+1)*8 : 0, n);
      unsigned* tk = ka; ka = kb; kb = tk;
      unsigned* tv = va; va = vb; vb = tv;
      int* tg = gcur; gcur = gnext; gnext = tg;
    }
    // after 4 passes sorted data is back in keys0/vals0 (va == vals0)
    k_ssx<<<(n*64+255)/256, 256, 0, stream>>>(va, g, x1, ssx, inv, n);
  }

  // conv1d x2
  k_wt<<<(2*20480+255)/256, 256, 0, stream>>>(cw1, cw2, wT1, wT2);
  k_conv<<<(n+127)/128, 256, 0, stream>>>(ssx, wT1, cb1, y1, n, 1);
  k_conv<<<(n+127)/128, 256, 0, stream>>>(y1, wT2, cb2, y2, n, 0);

  // fused concat -> GEMM -> bias -> log_softmax
  k_fgemm<<<nb64, 256, 0, stream>>>(x1, y2, inv, Wl, bl, out, n);
}

// Round 5
// 1374.331 us; speedup vs baseline: 1.1818x; 1.1818x over previous
//
#include <hip/hip_runtime.h>
#include <cstdint>
#include <cstddef>

// Problem constants (from reference): N=100000, F_IN=512, HID=256, C=64, E=3.2e6, K=5
#define NF_IN 512
#define NHID 256
#define NC 64

typedef _Float16 f16x8 __attribute__((ext_vector_type(8)));
typedef float f32x4 __attribute__((ext_vector_type(4)));

// ---------------- bucketized CSR build ----------------
// Buckets: dst>>8 (256 nodes/bucket). NBK = (n+255)>>8 <= 512.
__global__ void kb_hist(const int* __restrict__ dst, int e_total,
                        int* __restrict__ gh, int nbk){
  __shared__ int h[512];
  int t = threadIdx.x;
  for (int i=t;i<nbk;i+=256) h[i]=0;
  __syncthreads();
  int e0 = blockIdx.x*4096;
  #pragma unroll
  for (int j=0;j<16;j++){
    int e = e0 + j*256 + t;
    if (e < e_total) atomicAdd(&h[dst[e]>>8], 1);
  }
  __syncthreads();
  for (int i=t;i<nbk;i+=256) if (h[i]) atomicAdd(&gh[i], h[i]);
}

// single-block in-place exclusive scan (n <= 256*chunk)
__global__ void k_scan1(int* __restrict__ data, int n){
  __shared__ int P[256];
  int t = threadIdx.x;
  int chunk = (n + 255) >> 8;
  int base = t*chunk;
  int s = 0;
  for (int j=0;j<chunk;j++) if (base+j<n) s += data[base+j];
  P[t]=s; __syncthreads();
  for (int o=1;o<256;o<<=1){
    int v = (t>=o)? P[t-o]:0; __syncthreads();
    P[t]+=v; __syncthreads();
  }
  int run = (t>0)? P[t-1] : 0;
  for (int j=0;j<chunk;j++) if (base+j<n){ int v = data[base+j]; data[base+j]=run; run+=v; }
}

// exclusive scan + copy of scanned values into a cursor array
__global__ void kb_scan1c(int* __restrict__ data, int* __restrict__ cpy, int n){
  __shared__ int P[256];
  int t = threadIdx.x;
  int chunk = (n + 255) >> 8;
  int base = t*chunk;
  int s = 0;
  for (int j=0;j<chunk;j++) if (base+j<n) s += data[base+j];
  P[t]=s; __syncthreads();
  for (int o=1;o<256;o<<=1){
    int v = (t>=o)? P[t-o]:0; __syncthreads();
    P[t]+=v; __syncthreads();
  }
  int run = (t>0)? P[t-1] : 0;
  for (int j=0;j<chunk;j++) if (base+j<n){ int v = data[base+j]; data[base+j]=run; cpy[base+j]=run; run+=v; }
}

__global__ void kb_scatter(const int* __restrict__ src, const int* __restrict__ dst,
                           int e_total, int* __restrict__ bcur,
                           unsigned* __restrict__ pairs, int nbk){
  __shared__ int h[512];
  __shared__ int cb[512];
  int t = threadIdx.x;
  for (int i=t;i<nbk;i+=256) h[i]=0;
  __syncthreads();
  int e0 = blockIdx.x*4096;
  int d[16], s_[16];
  #pragma unroll
  for (int j=0;j<16;j++){
    int e = e0 + j*256 + t;
    if (e < e_total){ d[j]=dst[e]; s_[j]=src[e]; atomicAdd(&h[d[j]>>8],1); }
    else d[j] = -1;
  }
  __syncthreads();
  for (int i=t;i<nbk;i+=256){
    int c = h[i];
    cb[i] = c ? atomicAdd(&bcur[i], c) : 0;
    h[i] = 0;
  }
  __syncthreads();
  #pragma unroll
  for (int j=0;j<16;j++){
    if (d[j] >= 0){
      int bkt = d[j]>>8;
      int pos = cb[bkt] + atomicAdd(&h[bkt],1);
      pairs[pos] = ((unsigned)(d[j]&255)<<24) | (unsigned)s_[j];
    }
  }
}

__global__ __launch_bounds__(256) void kb_build(const unsigned* __restrict__ pairs,
    const int* __restrict__ bbase, int e_total, int nbk, int n,
    int* __restrict__ rowptr, int* __restrict__ cnt, float* __restrict__ dinv,
    int* __restrict__ csr){
  __shared__ int cL[256];
  __shared__ int sc[256];
  __shared__ int rpL[256];
  int b = blockIdx.x, t = threadIdx.x;
  int beg = bbase[b];
  int end = (b == nbk-1) ? e_total : bbase[b+1];
  cL[t] = 0; __syncthreads();
  for (int i=beg+t; i<end; i+=256) atomicAdd(&cL[pairs[i]>>24], 1);
  __syncthreads();
  int v = cL[t]; sc[t] = v; __syncthreads();
  for (int o=1;o<256;o<<=1){
    int w = (t>=o)? sc[t-o]:0; __syncthreads();
    sc[t] += w; __syncthreads();
  }
  rpL[t] = sc[t] - v;            // exclusive
  int node = b*256 + t;
  if (node < n){
    rowptr[node] = beg + rpL[t];
    cnt[node]    = v;
    dinv[node]   = 1.0f / sqrtf((float)(v + 1));
  }
  cL[t] = 0; __syncthreads();
  for (int i=beg+t; i<end; i+=256){
    unsigned p = pairs[i];
    int loc = p >> 24;
    int pos = beg + rpL[loc] + atomicAdd(&cL[loc], 1);
    csr[pos] = (int)(p & 0xFFFFFFu);
  }
}

// ---------------- W1 split: fp32 [K=512][N=256] -> hi/lo fp16 transposed [N][K] ----------------
__global__ void k_wsplit(const float* __restrict__ W, _Float16* __restrict__ WhT,
                         _Float16* __restrict__ WlT){
  int idx = blockIdx.x*256 + threadIdx.x;
  if (idx < NF_IN*NHID){
    int k = idx >> 8, nn = idx & 255;        // W row-major [512][256]
    float w = W[idx];
    _Float16 h = (_Float16)w;
    _Float16 l = (_Float16)((w - (float)h) * 2048.0f);
    WhT[(size_t)nn*NF_IN + k] = h;
    WlT[(size_t)nn*NF_IN + k] = l;
  }
}

// ---------------- split-fp16 MFMA GEMM for layer 1 (fp32-accurate) ----------------
__global__ __launch_bounds__(512, 2) void k_mgemm1(
    const float* __restrict__ A, int lda,
    const _Float16* __restrict__ BhT, const _Float16* __restrict__ BlT, int ldb,
    float* __restrict__ C, int ldc, int M, int K, const float* __restrict__ dinv){
  __shared__ __align__(16) _Float16 Ah[128*40];
  __shared__ __align__(16) _Float16 Al[128*40];
  __shared__ __align__(16) _Float16 Bh[256*40];
  __shared__ __align__(16) _Float16 Bl[256*40];
  int t = threadIdx.x;
  int m0 = blockIdx.x*128;
  int wave = t>>6, lane = t&63;
  int wm = (wave>>2)*64, wn = (wave&3)*64;

  int arow = t>>2, akb = (t&3)*8;
  int ga = m0 + arow; if (ga >= M) ga = M - 1;
  const float* aptr = A + (size_t)ga*lda + akb;
  int brow = t>>1, bkb = (t&1)*16;
  const _Float16* bhp = BhT + (size_t)brow*ldb + bkb;
  const _Float16* blp = BlT + (size_t)brow*ldb + bkb;

  float4 a0 = *(const float4*)(aptr);
  float4 a1 = *(const float4*)(aptr+4);
  f16x8  b0 = *(const f16x8*)(bhp);
  f16x8  b1 = *(const f16x8*)(bhp+8);
  f16x8  c0 = *(const f16x8*)(blp);
  f16x8  c1 = *(const f16x8*)(blp+8);

  f32x4 acc1[4][4] = {};   // hi*hi
  f32x4 acc2[4][4] = {};   // hi*lo' + lo'*hi (scaled by 2^11)

  for (int k0 = 0; k0 < K; k0 += 32){
    __syncthreads();
    {
      float av[8] = {a0.x,a0.y,a0.z,a0.w, a1.x,a1.y,a1.z,a1.w};
      f16x8 h0, l0;
      #pragma unroll
      for (int j=0;j<8;j++){
        _Float16 hh = (_Float16)av[j];
        h0[j] = hh;
        l0[j] = (_Float16)((av[j] - (float)hh) * 2048.0f);
      }
      *(f16x8*)&Ah[arow*40+akb] = h0;
      *(f16x8*)&Al[arow*40+akb] = l0;
      *(f16x8*)&Bh[brow*40+bkb]   = b0;
      *(f16x8*)&Bh[brow*40+bkb+8] = b1;
      *(f16x8*)&Bl[brow*40+bkb]   = c0;
      *(f16x8*)&Bl[brow*40+bkb+8] = c1;
    }
    __syncthreads();
    if (k0 + 32 < K){
      a0 = *(const float4*)(aptr + k0+32);
      a1 = *(const float4*)(aptr + k0+36);
      b0 = *(const f16x8*)(bhp + k0+32);
      b1 = *(const f16x8*)(bhp + k0+40);
      c0 = *(const f16x8*)(blp + k0+32);
      c1 = *(const f16x8*)(blp + k0+40);
    }
    int fr = lane & 15, fk = (lane>>4)*8;
    f16x8 afh[4], afl[4];
    #pragma unroll
    for (int mf=0; mf<4; mf++){
      afh[mf] = *(const f16x8*)&Ah[(wm + mf*16 + fr)*40 + fk];
      afl[mf] = *(const f16x8*)&Al[(wm + mf*16 + fr)*40 + fk];
    }
    #pragma unroll
    for (int nf=0; nf<4; nf++){
      f16x8 bfh = *(const f16x8*)&Bh[(wn + nf*16 + fr)*40 + fk];
      f16x8 bfl = *(const f16x8*)&Bl[(wn + nf*16 + fr)*40 + fk];
      #pragma unroll
      for (int mf=0; mf<4; mf++){
        acc1[mf][nf] = __builtin_amdgcn_mfma_f32_16x16x32_f16(afh[mf], bfh, acc1[mf][nf], 0, 0, 0);
        acc2[mf][nf] = __builtin_amdgcn_mfma_f32_16x16x32_f16(afh[mf], bfl, acc2[mf][nf], 0, 0, 0);
        acc2[mf][nf] = __builtin_amdgcn_mfma_f32_16x16x32_f16(afl[mf], bfh, acc2[mf][nf], 0, 0, 0);
      }
    }
  }

  int fr = lane & 15, fq = lane >> 4;
  #pragma unroll
  for (int mf=0; mf<4; mf++){
    #pragma unroll
    for (int i=0;i<4;i++){
      int row = m0 + wm + mf*16 + fq*4 + i;
      if (row < M){
        float sc = dinv ? dinv[row] : 1.0f;
        #pragma unroll
        for (int nf=0; nf<4; nf++){
          float v = (acc1[mf][nf][i] + 0.00048828125f*acc2[mf][nf][i]) * sc;
          C[(size_t)row*ldc + wn + nf*16 + fr] = v;
        }
      }
    }
  }
}

// ---------------- FUSED: GCN-1 aggregation + ReLU + (h @ W2) * dinv -> u2 ----------------
// Wave/node gather (8-deep pipelined) exactly as before; the h row never touches HBM:
// each wave writes its private hL[wave] LDS row and immediately computes the 256->64
// matvec against LDS-staged W2 (64KB). NO barriers in the main loop (waves touch only
// their own hL row) -> wave independence that saturates the gather fabric is preserved.
// Grid-stride: W2 staged once per block. LDS 72KB -> 2 blocks/CU (16 waves/CU).
__global__ __launch_bounds__(512, 4) void k_agg1f(const float* __restrict__ u,
    const int* __restrict__ rowptr, const int* __restrict__ cnt,
    const int* __restrict__ csr, const float* __restrict__ dinv,
    const float* __restrict__ bias, const float* __restrict__ W2,
    float* __restrict__ u2, int n){
  __shared__ float W2s[256*64];   // [c][j], 64KB
  __shared__ float hL[8][256];    // per-wave private h row
  int t = threadIdx.x;
  for (int i=t; i<256*64; i+=512) W2s[i] = W2[i];
  __syncthreads();
  int wave = t>>6, lane = t&63;
  const float4* up = (const float4*)u;
  int ngrp = (n + 7) >> 3;
  for (int grp = blockIdx.x; grp < ngrp; grp += gridDim.x){
    int wid = grp*8 + wave;
    if (wid >= n) continue;      // safe: no barriers below
    float4 a = up[(size_t)wid*64 + lane];       // self term
    float ax=a.x, ay=a.y, az=a.z, aw=a.w;
    int beg = rowptr[wid], num = cnt[wid];
    int e = 0;
    int nb = num >> 4;
    if (nb > 0){
      int my = csr[beg + (lane & 15)];
      float4 v[8], w[8];
      #pragma unroll
      for (int q=0;q<8;q++){ int s = __shfl(my, q); v[q] = up[(size_t)s*64 + lane]; }
      int b = 0;
      for (;;){
        #pragma unroll
        for (int q=0;q<8;q++){ int s = __shfl(my, q+8); w[q] = up[(size_t)s*64 + lane]; }
        #pragma unroll
        for (int q=0;q<8;q++){ ax+=v[q].x; ay+=v[q].y; az+=v[q].z; aw+=v[q].w; }
        b++;
        if (b >= nb){
          #pragma unroll
          for (int q=0;q<8;q++){ ax+=w[q].x; ay+=w[q].y; az+=w[q].z; aw+=w[q].w; }
          break;
        }
        my = csr[beg + b*16 + (lane & 15)];
        #pragma unroll
        for (int q=0;q<8;q++){ int s = __shfl(my, q); v[q] = up[(size_t)s*64 + lane]; }
        #pragma unroll
        for (int q=0;q<8;q++){ ax+=w[q].x; ay+=w[q].y; az+=w[q].z; aw+=w[q].w; }
      }
      e = nb*16;
    }
    for (; e+4 <= num; e+=4){
      int my = csr[beg + e + (lane & 3)];
      float4 v[4];
      #pragma unroll
      for (int q=0;q<4;q++){ int s = __shfl(my, q); v[q] = up[(size_t)s*64 + lane]; }
      #pragma unroll
      for (int q=0;q<4;q++){ ax+=v[q].x; ay+=v[q].y; az+=v[q].z; aw+=v[q].w; }
    }
    for (; e<num; e++){
      int sN = csr[beg+e];
      float4 v = up[(size_t)sN*64 + lane];
      ax+=v.x; ay+=v.y; az+=v.z; aw+=v.w;
    }
    float di = dinv[wid];
    float4 b = ((const float4*)bias)[lane];
    float4 hv;
    hv.x = fmaxf(di*ax + b.x, 0.f);
    hv.y = fmaxf(di*ay + b.y, 0.f);
    hv.z = fmaxf(di*az + b.z, 0.f);
    hv.w = fmaxf(di*aw + b.w, 0.f);
    ((float4*)hL[wave])[lane] = hv;   // own row; intra-wave dep handled by lgkmcnt
    // matvec: this wave's 64 lanes compute u2[wid][0..63]
    float acc = 0.f;
    #pragma unroll 8
    for (int c=0;c<256;c++) acc += hL[wave][c] * W2s[(c<<6) + lane];
    u2[(size_t)wid*64 + lane] = di * acc;
  }
}

// 64-channel aggregation + fused g-score / sort-key generation
__global__ __launch_bounds__(256) void k_agg2g(const float* __restrict__ u,
    const int* __restrict__ rowptr, const int* __restrict__ cnt,
    const int* __restrict__ csr, const float* __restrict__ dinv,
    const float* __restrict__ bias, float* __restrict__ outp, int n,
    const float* __restrict__ Wp, const float* __restrict__ bp,
    float* __restrict__ g, unsigned* __restrict__ keys, unsigned* __restrict__ vals){
  int wid = blockIdx.x*4 + (threadIdx.x>>6);
  int lane = threadIdx.x & 63;
  if (wid >= n) return;
  float acc = u[(size_t)wid*64 + lane];
  int beg = rowptr[wid], num = cnt[wid];
  int e = 0;
  for (; e+16 <= num; e+=16){
    int my = csr[beg + e + (lane & 15)];
    float v[16];
    #pragma unroll
    for (int q=0;q<16;q++){ int s = __shfl(my, q); v[q] = u[(size_t)s*64 + lane]; }
    #pragma unroll
    for (int q=0;q<16;q++) acc += v[q];
  }
  for (; e+4 <= num; e+=4){
    int my = csr[beg + e + (lane & 3)];
    float v[4];
    #pragma unroll
    for (int q=0;q<4;q++){ int s = __shfl(my, q); v[q] = u[(size_t)s*64 + lane]; }
    #pragma unroll
    for (int q=0;q<4;q++) acc += v[q];
  }
  for (; e<num; e++){
    int sN = csr[beg+e];
    acc += u[(size_t)sN*64 + lane];
  }
  float val = dinv[wid]*acc + bias[lane];
  outp[(size_t)wid*64 + lane] = val;
  float wv = val * Wp[lane];
  for (int o=32;o>0;o>>=1) wv += __shfl_xor(wv, o);
  if (lane == 0){
    float gg = wv + bp[0];
    g[wid] = gg;
    unsigned u_ = __float_as_uint(gg);
    u_ = (u_>>31) ? ~u_ : (u_ | 0x80000000u);
    keys[wid] = u_; vals[wid] = (unsigned)wid;
  }
}

// ---------------- stable 4-bit LSD radix sort (1024 elems/block) ----------------
__global__ void k_rhist(const unsigned* __restrict__ keys, int shift,
                        int* __restrict__ ghist, int n){
  __shared__ int h[16];
  int t = threadIdx.x;
  if (t < 16) h[t] = 0;
  __syncthreads();
  int base = blockIdx.x*1024 + t*4;
  #pragma unroll
  for (int j=0;j<4;j++)
    if (base+j < n){ int d = (keys[base+j]>>shift)&15; atomicAdd(&h[d],1); }
  __syncthreads();
  if (t < 16) ghist[t*gridDim.x + blockIdx.x] = h[t];
}

__global__ void k_rscatter(const unsigned* __restrict__ keys, const unsigned* __restrict__ vals,
                           int shift, const int* __restrict__ gbase,
                           unsigned* __restrict__ okeys, unsigned* __restrict__ ovals, int n){
  __shared__ int F[16*256];
  __shared__ int P[256];
  int t = threadIdx.x;
  int base = blockIdx.x*1024 + t*4;
  unsigned k[4]; int d[4];
  #pragma unroll
  for (int j=0;j<4;j++){
    bool ok = (base+j < n);
    k[j] = ok ? keys[base+j] : 0u;
    d[j] = (int)((k[j]>>shift)&15u);
    if (!ok) d[j] = -1;
  }
  #pragma unroll
  for (int dig=0;dig<16;dig++){
    int c = 0;
    #pragma unroll
    for (int j=0;j<4;j++) if (d[j]==dig) c++;
    F[dig*256 + t] = c;
  }
  __syncthreads();
  int loc[16]; int s = 0;
  #pragma unroll
  for (int q=0;q<16;q++){ loc[q] = F[t*16+q]; s += loc[q]; }
  P[t] = s; __syncthreads();
  for (int o=1;o<256;o<<=1){
    int v = (t>=o)? P[t-o]:0; __syncthreads();
    P[t] += v; __syncthreads();
  }
  int run = (t>0)? P[t-1] : 0;
  #pragma unroll
  for (int q=0;q<16;q++){ F[t*16+q] = run; run += loc[q]; }
  __syncthreads();
  #pragma unroll
  for (int j=0;j<4;j++){
    if (base+j < n){
      int dd = d[j];
      int r = 0;
      #pragma unroll
      for (int jj=0;jj<4;jj++) if (jj<j && d[jj]==dd) r++;
      int pos = gbase[dd*gridDim.x + blockIdx.x] + (F[dd*256 + t] - F[dd*256]) + r;
      okeys[pos] = k[j];
      ovals[pos] = vals[base+j];
    }
  }
}

// ---------------- sorted seq build, inverse perm ----------------
__global__ void k_ssx(const unsigned* __restrict__ sidx, const float* __restrict__ g,
                      const float* __restrict__ x1, float* __restrict__ ssx,
                      int* __restrict__ inv, int n){
  int idx = blockIdx.x*256 + threadIdx.x;
  if (idx < n*64){
    int p = idx>>6, c = idx&63;
    int j = (int)sidx[p];
    ssx[idx] = g[j] * x1[(size_t)j*64 + c];
    if (c==0) inv[j] = p;
  }
}

// conv weight transpose [co][ci][k] -> [k][ci][co]
__global__ void k_wt(const float* __restrict__ cw1, const float* __restrict__ cw2,
                     float* __restrict__ wT1, float* __restrict__ wT2){
  int idx = blockIdx.x*256 + threadIdx.x;
  if (idx < 2*20480){
    const float* s = (idx < 20480) ? cw1 : cw2;
    float* o = (idx < 20480) ? wT1 : wT2;
    int i = idx % 20480;
    int kk = i % 5, ci = (i/5) % 64, co = i / 320;
    o[((kk<<6)+ci)*64 + co] = s[i];
  }
}

// ---------------- direct conv1d, C=64, K=5, SAME ----------------
__global__ __launch_bounds__(256) void k_conv(const float* __restrict__ inp,
    const float* __restrict__ wT, const float* __restrict__ bias,
    float* __restrict__ outp, int n, int do_relu){
  __shared__ float xin[132*65];    // rows r0-2 .. r0+129, stride 65
  int t = threadIdx.x;
  int r0 = blockIdx.x*128;
  for (int idx=t; idx<132*64; idx+=256){
    int r = idx>>6, c = idx&63;
    int gr = r0 + r - 2;
    xin[r*65 + c] = (gr>=0 && gr<n) ? inp[(size_t)gr*64 + c] : 0.f;
  }
  __syncthreads();
  int rg = t & 15, cg = t >> 4;
  float acc[8][4] = {};
  for (int k=0;k<5;k++){
    for (int ci=0;ci<64;ci++){
      float4 w = *(const float4*)&wT[((k<<6)+ci)*64 + (cg<<2)];
      #pragma unroll
      for (int rr=0;rr<8;rr++){
        float xv = xin[(rg + (rr<<4) + k)*65 + ci];
        acc[rr][0] += xv*w.x; acc[rr][1] += xv*w.y;
        acc[rr][2] += xv*w.z; acc[rr][3] += xv*w.w;
      }
    }
  }
  float4 b = ((const float4*)bias)[cg];
  #pragma unroll
  for (int rr=0;rr<8;rr++){
    int row = r0 + rg + (rr<<4);
    if (row < n){
      float4 v;
      v.x = acc[rr][0]+b.x; v.y = acc[rr][1]+b.y; v.z = acc[rr][2]+b.z; v.w = acc[rr][3]+b.w;
      if (do_relu){ v.x=fmaxf(v.x,0.f); v.y=fmaxf(v.y,0.f); v.z=fmaxf(v.z,0.f); v.w=fmaxf(v.w,0.f); }
      *(float4*)&outp[(size_t)row*64 + (cg<<2)] = v;
    }
  }
}

// ---------------- fused final: [x1 | y2[inv]] @ Wl + bl -> log_softmax -> out ----------------
__global__ __launch_bounds__(256) void k_fgemm(const float* __restrict__ x1,
    const float* __restrict__ y2, const int* __restrict__ inv,
    const float* __restrict__ Wl, const float* __restrict__ bl,
    float* __restrict__ outp, int M){
  __shared__ float As[16*68];
  __shared__ float Bs[16*64];
  __shared__ float Pr[64*16];
  __shared__ float Ms[64];
  __shared__ float Ls[64];
  int t = threadIdx.x;
  int m0 = blockIdx.x*64;
  int tx = t & 15, ty = t >> 4;
  float acc[4][4] = {};
  int arow = m0 + (t>>2); if (arow >= M) arow = M-1;
  int acol0 = (t&3)*4;
  int invr = inv[arow];
  const float* bptr = Wl + (size_t)(t>>4)*64 + tx*4;
  for (int k0=0; k0<128; k0+=16){
    int acol = acol0 + k0;
    float4 av = (acol < 64) ? *(const float4*)&x1[(size_t)arow*64 + acol]
                            : *(const float4*)&y2[(size_t)invr*64 + (acol-64)];
    float4 bv = *(const float4*)(bptr + (size_t)k0*64);
    __syncthreads();
    int ak = (t&3)*4, ar = t>>2;
    As[(ak+0)*68 + ar] = av.x;
    As[(ak+1)*68 + ar] = av.y;
    As[(ak+2)*68 + ar] = av.z;
    As[(ak+3)*68 + ar] = av.w;
    *(float4*)&Bs[(t>>4)*64 + (t&15)*4] = bv;
    __syncthreads();
    #pragma unroll
    for (int kk=0;kk<16;kk++){
      float4 a4 = *(const float4*)&As[kk*68 + (ty<<2)];
      float4 b4 = *(const float4*)&Bs[(kk<<6) + (tx<<2)];
      float aa[4] = {a4.x,a4.y,a4.z,a4.w};
      float bb[4] = {b4.x,b4.y,b4.z,b4.w};
      #pragma unroll
      for (int i=0;i<4;i++)
        #pragma unroll
        for (int j=0;j<4;j++) acc[i][j] += aa[i]*bb[j];
    }
  }
  float v[4][4];
  #pragma unroll
  for (int i=0;i<4;i++)
    #pragma unroll
    for (int j=0;j<4;j++) v[i][j] = acc[i][j] + bl[(tx<<2)+j];
  #pragma unroll
  for (int i=0;i<4;i++){
    float pm = fmaxf(fmaxf(v[i][0],v[i][1]), fmaxf(v[i][2],v[i][3]));
    Pr[((ty<<2)+i)*16 + tx] = pm;
  }
  __syncthreads();
  if (t < 64){
    float m = Pr[t*16];
    #pragma unroll
    for (int k=1;k<16;k++) m = fmaxf(m, Pr[t*16+k]);
    Ms[t] = m;
  }
  __syncthreads();
  #pragma unroll
  for (int i=0;i<4;i++){
    float m = Ms[(ty<<2)+i];
    float ps = expf(v[i][0]-m)+expf(v[i][1]-m)+expf(v[i][2]-m)+expf(v[i][3]-m);
    Pr[((ty<<2)+i)*16 + tx] = ps;
  }
  __syncthreads();
  if (t < 64){
    float s = 0.f;
    #pragma unroll
    for (int k=0;k<16;k++) s += Pr[t*16+k];
    Ls[t] = logf(s);
  }
  __syncthreads();
  #pragma unroll
  for (int i=0;i<4;i++){
    int row = m0 + (ty<<2) + i;
    if (row < M){
      float m = Ms[(ty<<2)+i], l = Ls[(ty<<2)+i];
      float4 o;
      o.x = v[i][0]-m-l; o.y = v[i][1]-m-l; o.z = v[i][2]-m-l; o.w = v[i][3]-m-l;
      *(float4*)&outp[(size_t)row*64 + (tx<<2)] = o;
    }
  }
}

// ---------------- launch ----------------
extern "C" void kernel_launch(void* const* d_in, const int* in_sizes, int n_in,
                              void* d_out, int out_size, void* d_ws, size_t ws_size,
                              hipStream_t stream) {
  const float* x   = (const float*)d_in[0];
  const int*   ei  = (const int*)d_in[1];
  const float* W1  = (const float*)d_in[2];
  const float* b1  = (const float*)d_in[3];
  const float* W2  = (const float*)d_in[4];
  const float* b2  = (const float*)d_in[5];
  const float* Wp  = (const float*)d_in[6];
  const float* bp  = (const float*)d_in[7];
  const float* cw1 = (const float*)d_in[8];
  const float* cb1 = (const float*)d_in[9];
  const float* cw2 = (const float*)d_in[10];
  const float* cb2 = (const float*)d_in[11];
  const float* Wl  = (const float*)d_in[12];
  const float* bl  = (const float*)d_in[13];
  float* out = (float*)d_out;

  const int n = in_sizes[0] / NF_IN;        // 100000
  const int e_total = in_sizes[1] / 2;      // 3200000
  const int* srcp = ei;
  const int* dstp = ei + e_total;

  char* ws = (char*)d_ws;
  size_t off = 0;
  auto take = [&](size_t bytes)->char* {
    char* p = ws + off; off = (off + bytes + 255) & ~(size_t)255; return p;
  };
  const int NB  = (n + 1023) / 1024;        // radix-sort blocks (98)
  const int NBK = (n + 255) >> 8;           // CSR buckets (391), <= 512
  const int NEB = (e_total + 4095) / 4096;  // edge blocks (782)
  int*      cnt    = (int*)     take((size_t)n*4);
  int*      rowptr = (int*)     take((size_t)n*4);
  float*    dinv   = (float*)   take((size_t)n*4);
  float*    g      = (float*)   take((size_t)n*4);
  int*      inv    = (int*)     take((size_t)n*4);
  unsigned* keys0  = (unsigned*)take((size_t)n*4);
  unsigned* vals0  = (unsigned*)take((size_t)n*4);
  unsigned* keys1  = (unsigned*)take((size_t)n*4);
  unsigned* vals1  = (unsigned*)take((size_t)n*4);
  int*      ghist  = (int*)     take((size_t)(16*NB)*4);
  int*      bh     = (int*)     take(512*4);
  int*      bcur   = (int*)     take(512*4);
  int*      csr    = (int*)     take((size_t)e_total*4);
  float*    wT1    = (float*)   take(20480*4);
  float*    wT2    = (float*)   take(20480*4);
  _Float16* w1h    = (_Float16*)take((size_t)NF_IN*NHID*2);
  _Float16* w1l    = (_Float16*)take((size_t)NF_IN*NHID*2);
  float*    bigA   = (float*)   take((size_t)n*256*4);
  float*    bigB   = (float*)   take((size_t)n*256*4);
  unsigned* pairs  = (unsigned*)bigA;       // transient: consumed before u1 written
  float* u1  = bigA;                        // [n*256], dead after k_agg1f
  float* x1  = bigA + (size_t)n*64;
  float* ssx = bigA + (size_t)n*128;
  float* y1  = bigA + (size_t)n*192;
  float* u2  = bigB;                        // [n*64], dead after k_agg2g
  float* y2  = bigB + (size_t)n*64;

  const int nb128 = (n + 127) / 128;
  const int nb64  = (n + 63) / 64;
  const int nbAgg = (n + 3) / 4;

  // bucketized CSR build (+ cnt/rowptr/dinv)
  hipMemsetAsync(bh, 0, (size_t)NBK*4, stream);
  kb_hist<<<NEB, 256, 0, stream>>>(dstp, e_total, bh, NBK);
  kb_scan1c<<<1, 256, 0, stream>>>(bh, bcur, NBK);
  kb_scatter<<<NEB, 256, 0, stream>>>(srcp, dstp, e_total, bcur, pairs, NBK);
  kb_build<<<NBK, 256, 0, stream>>>(pairs, bh, e_total, NBK, n, rowptr, cnt, dinv, csr);

  // GCN layer 1: u1 = dinv .* (x @ W1) via split-fp16 MFMA (BN=256, A read once)
  k_wsplit<<<(NF_IN*NHID+255)/256, 256, 0, stream>>>(W1, w1h, w1l);
  k_mgemm1<<<dim3(nb128, 1), 512, 0, stream>>>(x, NF_IN, w1h, w1l, NF_IN, u1, NHID, n, NF_IN, dinv);

  // FUSED: h = relu(agg(u1)+b1) stays in LDS; u2 = dinv .* (h @ W2) written directly
  k_agg1f<<<512, 512, 0, stream>>>(u1, rowptr, cnt, csr, dinv, b1, W2, u2, n);

  // GCN layer 2 aggregation: x1 = agg(u2) + b2 (+ fused g-score/sort keys)
  k_agg2g<<<nbAgg, 256, 0, stream>>>(u2, rowptr, cnt, csr, dinv, b2, x1, n,
                                     Wp, bp, g, keys0, vals0);

  // stable radix sort, 8 x 4-bit passes (proven-fast variant)
  unsigned *ka = keys0, *va = vals0, *kb = keys1, *vb = vals1;
  for (int p = 0; p < 8; p++){
    k_rhist<<<NB, 256, 0, stream>>>(ka, p*4, ghist, n);
    k_scan1<<<1, 256, 0, stream>>>(ghist, 16*NB);
    k_rscatter<<<NB, 256, 0, stream>>>(ka, va, p*4, ghist, kb, vb, n);
    unsigned* tk = ka; ka = kb; kb = tk;
    unsigned* tv = va; va = vb; vb = tv;
  }

  // sorted sequence + inverse permutation (va = sorted node indices)
  k_ssx<<<(n*64+255)/256, 256, 0, stream>>>(va, g, x1, ssx, inv, n);

  // conv1d x2
  k_wt<<<(2*20480+255)/256, 256, 0, stream>>>(cw1, cw2, wT1, wT2);
  k_conv<<<(n+127)/128, 256, 0, stream>>>(ssx, wT1, cb1, y1, n, 1);
  k_conv<<<(n+127)/128, 256, 0, stream>>>(y1, wT2, cb2, y2, n, 0);

  // fused concat -> GEMM -> bias -> log_softmax
  k_fgemm<<<nb64, 256, 0, stream>>>(x1, y2, inv, Wl, bl, out, n);
}